// Round 3
// baseline (7532.675 us; speedup 1.0000x reference)
//
#include <hip/hip_runtime.h>

#define TSTEPS 50
#define NB (2048 * 256)   // floats per h half-plane (256 rows x 2048 seqs)

__device__ __forceinline__ float sigm(float x) { return 1.0f / (1.0f + expf(-x)); }
__device__ __forceinline__ float gelu_t(float x) {
  float x3 = x * x * x;
  return 0.5f * x * (1.0f + tanhf(0.7978845608028654f * (x + 0.044715f * x3)));
}

#define FMA16(a, w) do { \
  z[0][0] += (a).x*(w).x; z[0][1] += (a).x*(w).y; z[0][2] += (a).x*(w).z; z[0][3] += (a).x*(w).w; \
  z[1][0] += (a).y*(w).x; z[1][1] += (a).y*(w).y; z[1][2] += (a).y*(w).z; z[1][3] += (a).y*(w).w; \
  z[2][0] += (a).z*(w).x; z[2][1] += (a).z*(w).y; z[2][2] += (a).z*(w).z; z[2][3] += (a).z*(w).w; \
  z[3][0] += (a).w*(w).x; z[3][1] += (a).w*(w).y; z[3][2] += (a).w*(w).z; z[3][3] += (a).w*(w).w; \
} while (0)

// per-m-group barrier: 32 blocks share one counter; monotonic target per phase.
__device__ __forceinline__ void mg_barrier(unsigned* bar, unsigned target) {
  __syncthreads();
  if (threadIdx.x == 0) {
    __threadfence();
    atomicAdd(bar, 1u);
    while (atomicAdd(bar, 0u) < target) __builtin_amdgcn_s_sleep(2);
    __threadfence();
  }
  __syncthreads();
}

// Pack W into per-block-contiguous layout Wp[jg][k][jj*4+g]; zero barrier counters.
__global__ void __launch_bounds__(256)
pack_w(const float* __restrict__ Wx1, const float* __restrict__ Wh1,
       const float* __restrict__ Wx2, const float* __restrict__ Wh2,
       float* __restrict__ Wp1, float* __restrict__ Wp2, unsigned* __restrict__ bar) {
  const int idx = blockIdx.x * 256 + threadIdx.x;
  if (blockIdx.x == 0 && threadIdx.x < 256) bar[threadIdx.x] = 0u;
  if (idx < 32 * 272 * 32) {
    int c = idx & 31, k = (idx >> 5) % 272, jg = idx / (272 * 32);
    int col = ((c & 3) << 8) + (jg << 3) + (c >> 2);      // g*256 + jg*8 + jj
    Wp1[idx] = (k < 16) ? Wx1[(k << 10) + col] : Wh1[((k - 16) << 10) + col];
  }
  if (idx < 32 * 512 * 32) {
    int c = idx & 31, k = (idx >> 5) & 511, jg = idx >> 14;
    int col = ((c & 3) << 8) + (jg << 3) + (c >> 2);
    Wp2[idx] = (k < 256) ? Wx2[(k << 10) + col] : Wh2[((k - 256) << 10) + col];
  }
}

// Persistent 2-layer LSTM + time-mean pool. No LDS: A and W stream from L2
// with depth-8 register prefetch. grid 256 = 8 mg x 32 jg; block 512 thr.
// h pair buffers: pr[i] = [h1 rows 0..255 | h2 rows 256..511], each row 2048 seqs.
// Phase p reads pr[(p+1)&1], writes pr[p&1]; one mg_barrier per phase.
__global__ void __launch_bounds__(512, 1)
lstm_fused(const float* __restrict__ xin,
           const float* __restrict__ Wp1, const float* __restrict__ Wp2,
           const float* __restrict__ b1, const float* __restrict__ b2,
           float* __restrict__ pair0, float* __restrict__ pair1,
           float* __restrict__ xg, unsigned* __restrict__ bar)
{
  const int tid = threadIdx.x;
  const int blk = blockIdx.x;
  const int mg = blk >> 5, jg = blk & 31;
  const int mbase = mg << 8;
  const int ng = tid & 7;                 // hidden col within jg
  const int m0 = (tid >> 3) << 2;         // 4 consecutive seqs
  const int jcol = (jg << 3) + ng;
  const int mo = mbase + m0;
  unsigned* mybar = bar + (mg << 5);

  const float* wp1 = Wp1 + (size_t)jg * (272 * 32) + (ng << 2);
  const float* wp2 = Wp2 + (size_t)jg * (512 * 32) + (ng << 2);

  float4 zb1, zb2;
  zb1.x = b1[jcol]; zb1.y = b1[256 + jcol]; zb1.z = b1[512 + jcol]; zb1.w = b1[768 + jcol];
  zb2.x = b2[jcol]; zb2.y = b2[256 + jcol]; zb2.z = b2[512 + jcol]; zb2.w = b2[768 + jcol];

  float c1[4] = {0, 0, 0, 0}, c2[4] = {0, 0, 0, 0}, pool[4] = {0, 0, 0, 0};
  float* const pr[2] = { pair0, pair1 };

  // x gather: A[k][m0+i] = x[(mo+i)*800 + p*16 + k], stride 800 across m
  const float* xrow = xin + (size_t)mo * 800;

  for (int p = 0; p <= TSTEPS; ++p) {
    float* const pw = pr[p & 1];
    const float* const prd = pr[(p + 1) & 1];

    // ---------------- Layer 1: h1[p] = cell(x[p], h1[p-1]) ----------------
    if (p < TSTEPS) {
      float z[4][4];
      #pragma unroll
      for (int mi = 0; mi < 4; ++mi) {
        z[mi][0] = zb1.x; z[mi][1] = zb1.y; z[mi][2] = zb1.z; z[mi][3] = zb1.w;
      }
      const float* xb = xrow + p * 16;
      auto ldx = [&](int kk) {
        float4 a;
        a.x = xb[kk]; a.y = xb[800 + kk]; a.z = xb[1600 + kk]; a.w = xb[2400 + kk];
        return a;
      };
      float4 Aq[8], Wq[8];
      #pragma unroll
      for (int i = 0; i < 8; ++i) {
        Aq[i] = ldx(i);
        Wq[i] = *(const float4*)(wp1 + i * 32);
      }
      if (p == 0) {                        // only the x chunk (16 k)
        #pragma unroll 8
        for (int k = 0; k < 16; ++k) {
          float4 a = Aq[k & 7], w = Wq[k & 7];
          FMA16(a, w);
          int kn = k + 8; kn = kn > 15 ? 15 : kn;
          Aq[k & 7] = ldx(kn);
          Wq[k & 7] = *(const float4*)(wp1 + kn * 32);
        }
      } else {
        #pragma unroll                      // peel k=0..7, refill x rows 8..15
        for (int k = 0; k < 8; ++k) {
          float4 a = Aq[k], w = Wq[k];
          FMA16(a, w);
          Aq[k] = ldx(k + 8);
          Wq[k] = *(const float4*)(wp1 + (k + 8) * 32);
        }
        #pragma unroll 8                    // main: refill h1prev rows (kn-16)
        for (int k = 8; k < 272; ++k) {
          float4 a = Aq[k & 7], w = Wq[k & 7];
          FMA16(a, w);
          int kn = k + 8; kn = kn > 271 ? 271 : kn;
          Aq[k & 7] = *(const float4*)(prd + (size_t)(kn - 16) * 2048 + mo);
          Wq[k & 7] = *(const float4*)(wp1 + kn * 32);
        }
      }
      float4 hv;
      #pragma unroll
      for (int mi = 0; mi < 4; ++mi) {
        float iv = sigm(z[mi][0]), fv = sigm(z[mi][1]);
        float gv = tanhf(z[mi][2]), ov = sigm(z[mi][3]);
        c1[mi] = fv * c1[mi] + iv * gv;
        (&hv.x)[mi] = ov * tanhf(c1[mi]);
      }
      *(float4*)(pw + (size_t)jcol * 2048 + mo) = hv;
    }

    // ---------------- Layer 2: h2[p-1] = cell(h1[p-1], h2[p-2]) -----------
    if (p >= 1) {
      float z[4][4];
      #pragma unroll
      for (int mi = 0; mi < 4; ++mi) {
        z[mi][0] = zb2.x; z[mi][1] = zb2.y; z[mi][2] = zb2.z; z[mi][3] = zb2.w;
      }
      const int NK = (p == 1) ? 256 : 512;  // p==1: h2[-1]==0, skip rows 256..511
      float4 Aq[8], Wq[8];
      #pragma unroll
      for (int i = 0; i < 8; ++i) {
        Aq[i] = *(const float4*)(prd + (size_t)i * 2048 + mo);
        Wq[i] = *(const float4*)(wp2 + i * 32);
      }
      #pragma unroll 8
      for (int k = 0; k < NK; ++k) {
        float4 a = Aq[k & 7], w = Wq[k & 7];
        FMA16(a, w);
        int kn = k + 8; kn = kn >= NK ? NK - 1 : kn;
        Aq[k & 7] = *(const float4*)(prd + (size_t)kn * 2048 + mo);
        Wq[k & 7] = *(const float4*)(wp2 + kn * 32);
      }
      float4 hv;
      #pragma unroll
      for (int mi = 0; mi < 4; ++mi) {
        float iv = sigm(z[mi][0]), fv = sigm(z[mi][1]);
        float gv = tanhf(z[mi][2]), ov = sigm(z[mi][3]);
        c2[mi] = fv * c2[mi] + iv * gv;
        float h = ov * tanhf(c2[mi]);
        pool[mi] += h;
        (&hv.x)[mi] = h;
      }
      *(float4*)(pw + (size_t)(256 + jcol) * 2048 + mo) = hv;
    }

    if (p < TSTEPS) mg_barrier(mybar, (unsigned)(p + 1) * 32u);
  }
  #pragma unroll
  for (int mi = 0; mi < 4; ++mi)
    xg[(size_t)(mo + mi) * 256 + jcol] = pool[mi] * (1.0f / 50.0f);  // [seq][256]
}

// ---- GAT (unchanged from round 2, verified) ------------------------------
__global__ void __launch_bounds__(256)
gat_feat(const float* __restrict__ xin, const float* __restrict__ gW,
         const float* __restrict__ a_src, const float* __restrict__ a_dst,
         float* __restrict__ hfeat, float* __restrict__ es, float* __restrict__ ed)
{
  __shared__ float Xs[8][260];
  const int tid = threadIdx.x;
  const int r0 = blockIdx.x << 3;
  #pragma unroll
  for (int i = 0; i < 8; ++i) Xs[i][tid] = xin[((r0 + i) << 8) + tid];
  __syncthreads();
  float acc[8];
  #pragma unroll
  for (int i = 0; i < 8; ++i) acc[i] = 0.0f;
  for (int k = 0; k < 256; k += 4) {
    const float w0 = gW[(k + 0) * 256 + tid];
    const float w1 = gW[(k + 1) * 256 + tid];
    const float w2 = gW[(k + 2) * 256 + tid];
    const float w3 = gW[(k + 3) * 256 + tid];
    #pragma unroll
    for (int i = 0; i < 8; ++i)
      acc[i] += Xs[i][k] * w0 + Xs[i][k + 1] * w1 + Xs[i][k + 2] * w2 + Xs[i][k + 3] * w3;
  }
  const int h = tid >> 6;
  const int lane = tid & 63;
  const float asv = a_src[(h << 6) + lane];
  const float adv = a_dst[(h << 6) + lane];
  #pragma unroll
  for (int i = 0; i < 8; ++i) {
    hfeat[((r0 + i) << 8) + tid] = acc[i];
    float pse = acc[i] * asv;
    float pde = acc[i] * adv;
    #pragma unroll
    for (int off = 32; off > 0; off >>= 1) {
      pse += __shfl_down(pse, off);
      pde += __shfl_down(pde, off);
    }
    if (lane == 0) {
      es[((r0 + i) << 2) + h] = pse;
      ed[((r0 + i) << 2) + h] = pde;
    }
  }
}

__global__ void __launch_bounds__(256)
gat_out(const float* __restrict__ hfeat, const float* __restrict__ es, const float* __restrict__ ed,
        const float* __restrict__ gb, float* __restrict__ yout)
{
  __shared__ float exs[32][4];
  __shared__ float invden[4];
  const int tid = threadIdx.x;
  const int rbase = blockIdx.x << 5;
  if (tid < 128) {
    const int u = tid >> 2, h = tid & 3;
    float l = es[((rbase + u) << 2) + h] + ed[(rbase << 2) + h];
    exs[u][h] = (l < 0.0f) ? 0.2f * l : l;
  }
  __syncthreads();
  if (tid < 4) {
    const int h = tid;
    float m = -1e30f;
    for (int u = 0; u < 32; ++u) m = fmaxf(m, exs[u][h]);
    float s = 0.0f;
    for (int u = 0; u < 32; ++u) { float e = expf(exs[u][h] - m); exs[u][h] = e; s += e; }
    s += exs[0][h];                        // duplicate 0->0 edge
    invden[h] = 1.0f / (s + 1e-9f);
  }
  __syncthreads();
  const int h = tid >> 6;
  const float h0 = hfeat[(rbase << 8) + tid];
  float s = exs[0][h] * h0;
  for (int u = 0; u < 32; ++u)
    s += exs[u][h] * hfeat[((rbase + u) << 8) + tid];
  const float bias = gb[tid];
  const float inv1 = 1.0f / (1.0f + 1e-9f);
  yout[(rbase << 8) + tid] = gelu_t(s * invden[h] + bias);
  const float gv = gelu_t(h0 * inv1 + bias);
  for (int v = 1; v < 32; ++v)
    yout[((rbase + v) << 8) + tid] = gv;
}

// ---- launch -------------------------------------------------------------
extern "C" void kernel_launch(void* const* d_in, const int* in_sizes, int n_in,
                              void* d_out, int out_size, void* d_ws, size_t ws_size,
                              hipStream_t stream) {
  (void)in_sizes; (void)n_in; (void)out_size; (void)ws_size;
  const float* states = (const float*)d_in[0];
  const float* Wx1 = (const float*)d_in[1];
  const float* Wh1 = (const float*)d_in[2];
  const float* b1  = (const float*)d_in[3];
  const float* Wx2 = (const float*)d_in[4];
  const float* Wh2 = (const float*)d_in[5];
  const float* b2  = (const float*)d_in[6];
  const float* gW1 = (const float*)d_in[7];
  const float* gas1 = (const float*)d_in[8];
  const float* gad1 = (const float*)d_in[9];
  const float* gb1 = (const float*)d_in[10];
  const float* gW2 = (const float*)d_in[11];
  const float* gas2 = (const float*)d_in[12];
  const float* gad2 = (const float*)d_in[13];
  const float* gb2 = (const float*)d_in[14];

  float* ws = (float*)d_ws;
  float* pair0 = ws;                       // 2*NB floats
  float* pair1 = ws + 2 * (size_t)NB;      // 2*NB floats
  float* xg    = ws + 4 * (size_t)NB;      // NB floats
  float* Wp1   = ws + 5 * (size_t)NB;      // 32*272*32 = 278528
  float* Wp2   = Wp1 + 278528;             // 32*512*32 = 524288
  unsigned* bar = (unsigned*)(Wp2 + 524288);
  // GAT scratch aliases (h pair buffers are dead after lstm_fused)
  float* y1    = pair0;
  float* hfeat = pair0 + NB;
  float* es    = pair1;
  float* ed    = pair1 + 2048 * 4;
  float* dout  = (float*)d_out;

  pack_w<<<dim3(2048), dim3(256), 0, stream>>>(Wx1, Wh1, Wx2, Wh2, Wp1, Wp2, bar);

  void* args[] = { (void*)&states, (void*)&Wp1, (void*)&Wp2, (void*)&b1, (void*)&b2,
                   (void*)&pair0, (void*)&pair1, (void*)&xg, (void*)&bar };
  hipError_t err = hipLaunchCooperativeKernel((void*)lstm_fused, dim3(256), dim3(512),
                                              args, 0, stream);
  (void)err;

  gat_feat<<<dim3(256), dim3(256), 0, stream>>>(xg, gW1, gas1, gad1, hfeat, es, ed);
  gat_out<<<dim3(64), dim3(256), 0, stream>>>(hfeat, es, ed, gb1, y1);
  gat_feat<<<dim3(256), dim3(256), 0, stream>>>(y1, gW2, gas2, gad2, hfeat, es, ed);
  gat_out<<<dim3(64), dim3(256), 0, stream>>>(hfeat, es, ed, gb2, dout);
}

// Round 4
// 4887.270 us; speedup vs baseline: 1.5413x; 1.5413x over previous
//
#include <hip/hip_runtime.h>

#define TSTEPS 50
#define NB (2048 * 256)   // floats per h half-plane

__device__ __forceinline__ float sigm(float x) { return 1.0f / (1.0f + expf(-x)); }
__device__ __forceinline__ float gelu_t(float x) {
  float x3 = x * x * x;
  return 0.5f * x * (1.0f + tanhf(0.7978845608028654f * (x + 0.044715f * x3)));
}

#define FMA16(a, w) do { \
  z[0][0] += (a).x*(w).x; z[0][1] += (a).x*(w).y; z[0][2] += (a).x*(w).z; z[0][3] += (a).x*(w).w; \
  z[1][0] += (a).y*(w).x; z[1][1] += (a).y*(w).y; z[1][2] += (a).y*(w).z; z[1][3] += (a).y*(w).w; \
  z[2][0] += (a).z*(w).x; z[2][1] += (a).z*(w).y; z[2][2] += (a).z*(w).z; z[2][3] += (a).z*(w).w; \
  z[3][0] += (a).w*(w).x; z[3][1] += (a).w*(w).y; z[3][2] += (a).w*(w).z; z[3][3] += (a).w*(w).w; \
} while (0)

// per-m-group barrier: 32 blocks (one XCD) share one counter; monotonic target.
__device__ __forceinline__ void mg_barrier(unsigned* bar, unsigned target) {
  __syncthreads();
  if (threadIdx.x == 0) {
    __threadfence();
    atomicAdd(bar, 1u);
    while (atomicAdd(bar, 0u) < target) __builtin_amdgcn_s_sleep(8);
    __threadfence();
  }
  __syncthreads();
}

// Pack W per (jg,ng) wave stream: Wp[(jg*8+ng)][k][4 gates]; zero barrier counters.
__global__ void __launch_bounds__(256)
pack_w(const float* __restrict__ Wx1, const float* __restrict__ Wh1,
       const float* __restrict__ Wx2, const float* __restrict__ Wh2,
       float* __restrict__ Wp1, float* __restrict__ Wp2, unsigned* __restrict__ bar) {
  const int idx = blockIdx.x * 256 + threadIdx.x;
  if (blockIdx.x == 0 && threadIdx.x < 256) bar[threadIdx.x] = 0u;
  if (idx < 256 * 272 * 4) {
    int g = idx & 3, k = (idx >> 2) % 272, c = idx / (272 * 4);   // c = jg*8+ng
    int col = (g << 8) + c;
    Wp1[idx] = (k < 16) ? Wx1[(k << 10) + col] : Wh1[((k - 16) << 10) + col];
  }
  if (idx < 256 * 512 * 4) {
    int g = idx & 3, k = (idx >> 2) & 511, c = idx >> 11;
    int col = (g << 8) + c;
    Wp2[idx] = (k < 256) ? Wx2[(k << 10) + col] : Wh2[((k - 256) << 10) + col];
  }
}

// x[seq][t*16+d] -> xT[t*16+d][seq]
__global__ void __launch_bounds__(256)
transpose_x(const float* __restrict__ x, float* __restrict__ xT) {
  __shared__ float Ts[64][65];
  const int st = blockIdx.x & 31;
  const int tt = blockIdx.x >> 5;
  const int s0 = st << 6, t0 = tt << 6;
  const int r = threadIdx.x >> 6;
  const int c = threadIdx.x & 63;
  #pragma unroll
  for (int i = 0; i < 16; ++i) {
    int row = r + (i << 2);
    int td = t0 + c;
    if (td < 800) Ts[row][c] = x[(s0 + row) * 800 + td];
  }
  __syncthreads();
  #pragma unroll
  for (int i = 0; i < 16; ++i) {
    int row = r + (i << 2);
    int td = t0 + row;
    if (td < 800) xT[td * 2048 + s0 + c] = Ts[c][row];
  }
}

// Persistent 2-layer LSTM + time-mean pool.
// grid 256: mg = blk&7 (XCD-aligned!), jg = blk>>3. block 512 thr = 8 waves.
// wave wv owns hidden col jcol = jg*8+wv; lanes cover 256 seqs (4 each).
// A-loads coalesced 1KB/wave (8-way L1 reuse across waves); W wave-uniform
// (scalar path). No LDS, no intra-phase syncs; depth-16 prefetch covers HBM.
__global__ void __launch_bounds__(512, 1)
lstm_fused(const float* __restrict__ xT,
           const float* __restrict__ Wp1, const float* __restrict__ Wp2,
           const float* __restrict__ b1, const float* __restrict__ b2,
           float* __restrict__ pair0, float* __restrict__ pair1,
           float* __restrict__ xg, unsigned* __restrict__ bar)
{
  __shared__ float lds_pad[24576];          // 96KB: force 1 block/CU
  if (blockDim.x == 0) lds_pad[threadIdx.x] = 1.0f;

  const int tid = threadIdx.x;
  const int blk = blockIdx.x;
  const int mg = blk & 7, jg = blk >> 3;    // XCD(blk)=blk%8=mg
  const int mbase = mg << 8;
  const int lane = tid & 63;
  const int wvu = __builtin_amdgcn_readfirstlane(tid >> 6);  // uniform wave id
  const int jcol = (jg << 3) + wvu;
  const int mo = mbase + (lane << 2);       // 4 consecutive seqs per lane
  unsigned* mybar = bar + (mg << 5);

  const float* wp1 = Wp1 + (size_t)(jcol) * (272 * 4);   // [k][4g] stream
  const float* wp2 = Wp2 + (size_t)(jcol) * (512 * 4);

  float4 zb1, zb2;
  zb1.x = b1[jcol]; zb1.y = b1[256 + jcol]; zb1.z = b1[512 + jcol]; zb1.w = b1[768 + jcol];
  zb2.x = b2[jcol]; zb2.y = b2[256 + jcol]; zb2.z = b2[512 + jcol]; zb2.w = b2[768 + jcol];

  float c1[4] = {0,0,0,0}, c2[4] = {0,0,0,0}, pool[4] = {0,0,0,0};
  float* const pr[2] = { pair0, pair1 };

  auto ldA = [&](const float* plane, int row) {
    return *(const float4*)(plane + (size_t)row * 2048 + mo);
  };

  for (int p = 0; p <= TSTEPS; ++p) {
    float* const pw = pr[p & 1];
    const float* const prd = pr[(p + 1) & 1];

    // ---- Layer 1: h1[p] = cell(x[p], h1[p-1]); A rows: 16 xT + 256 h1prev ----
    if (p < TSTEPS) {
      float z[4][4];
      #pragma unroll
      for (int mi = 0; mi < 4; ++mi) {
        z[mi][0] = zb1.x; z[mi][1] = zb1.y; z[mi][2] = zb1.z; z[mi][3] = zb1.w;
      }
      const float* xrows = xT + (size_t)(p * 16) * 2048;
      float4 Aq[16], Wq[16];
      #pragma unroll
      for (int i = 0; i < 16; ++i) {
        Aq[i] = ldA(xrows, i);
        Wq[i] = *(const float4*)(wp1 + (i << 2));
      }
      if (p == 0) {
        #pragma unroll
        for (int k = 0; k < 16; ++k) { float4 a = Aq[k], w = Wq[k]; FMA16(a, w); }
      } else {
        #pragma unroll 16
        for (int k = 0; k < 272; ++k) {
          float4 a = Aq[k & 15], w = Wq[k & 15];
          FMA16(a, w);
          int kn = k + 16; kn = kn > 271 ? 271 : kn;
          Aq[k & 15] = ldA(prd, kn - 16);            // h1prev rows 0..255
          Wq[k & 15] = *(const float4*)(wp1 + (kn << 2));
        }
      }
      float4 hv;
      #pragma unroll
      for (int mi = 0; mi < 4; ++mi) {
        float iv = sigm(z[mi][0]), fv = sigm(z[mi][1]);
        float gv = tanhf(z[mi][2]), ov = sigm(z[mi][3]);
        c1[mi] = fv * c1[mi] + iv * gv;
        (&hv.x)[mi] = ov * tanhf(c1[mi]);
      }
      *(float4*)(pw + (size_t)jcol * 2048 + mo) = hv;
    }

    // ---- Layer 2: h2[p-1] = cell(h1[p-1], h2[p-2]); A = prd rows 0..511 ----
    if (p >= 1) {
      float z[4][4];
      #pragma unroll
      for (int mi = 0; mi < 4; ++mi) {
        z[mi][0] = zb2.x; z[mi][1] = zb2.y; z[mi][2] = zb2.z; z[mi][3] = zb2.w;
      }
      const int NK = (p == 1) ? 256 : 512;           // p==1: h2[-1]==0
      float4 Aq[16], Wq[16];
      #pragma unroll
      for (int i = 0; i < 16; ++i) {
        Aq[i] = ldA(prd, i);
        Wq[i] = *(const float4*)(wp2 + (i << 2));
      }
      #pragma unroll 16
      for (int k = 0; k < NK; ++k) {
        float4 a = Aq[k & 15], w = Wq[k & 15];
        FMA16(a, w);
        int kn = k + 16; kn = kn >= NK ? NK - 1 : kn;
        Aq[k & 15] = ldA(prd, kn);
        Wq[k & 15] = *(const float4*)(wp2 + (kn << 2));
      }
      float4 hv;
      #pragma unroll
      for (int mi = 0; mi < 4; ++mi) {
        float iv = sigm(z[mi][0]), fv = sigm(z[mi][1]);
        float gv = tanhf(z[mi][2]), ov = sigm(z[mi][3]);
        c2[mi] = fv * c2[mi] + iv * gv;
        float h = ov * tanhf(c2[mi]);
        pool[mi] += h;
        (&hv.x)[mi] = h;
      }
      *(float4*)(pw + (size_t)(256 + jcol) * 2048 + mo) = hv;
    }

    if (p < TSTEPS) mg_barrier(mybar, (unsigned)(p + 1) * 32u);
  }
  #pragma unroll
  for (int mi = 0; mi < 4; ++mi)
    xg[(size_t)(mo + mi) * 256 + jcol] = pool[mi] * (1.0f / 50.0f);  // [seq][256]
}

// ---- GAT (verified R1/R2) -------------------------------------------------
__global__ void __launch_bounds__(256)
gat_feat(const float* __restrict__ xin, const float* __restrict__ gW,
         const float* __restrict__ a_src, const float* __restrict__ a_dst,
         float* __restrict__ hfeat, float* __restrict__ es, float* __restrict__ ed)
{
  __shared__ float Xs[8][260];
  const int tid = threadIdx.x;
  const int r0 = blockIdx.x << 3;
  #pragma unroll
  for (int i = 0; i < 8; ++i) Xs[i][tid] = xin[((r0 + i) << 8) + tid];
  __syncthreads();
  float acc[8];
  #pragma unroll
  for (int i = 0; i < 8; ++i) acc[i] = 0.0f;
  for (int k = 0; k < 256; k += 4) {
    const float w0 = gW[(k + 0) * 256 + tid];
    const float w1 = gW[(k + 1) * 256 + tid];
    const float w2 = gW[(k + 2) * 256 + tid];
    const float w3 = gW[(k + 3) * 256 + tid];
    #pragma unroll
    for (int i = 0; i < 8; ++i)
      acc[i] += Xs[i][k] * w0 + Xs[i][k + 1] * w1 + Xs[i][k + 2] * w2 + Xs[i][k + 3] * w3;
  }
  const int h = tid >> 6;
  const int lane = tid & 63;
  const float asv = a_src[(h << 6) + lane];
  const float adv = a_dst[(h << 6) + lane];
  #pragma unroll
  for (int i = 0; i < 8; ++i) {
    hfeat[((r0 + i) << 8) + tid] = acc[i];
    float pse = acc[i] * asv;
    float pde = acc[i] * adv;
    #pragma unroll
    for (int off = 32; off > 0; off >>= 1) {
      pse += __shfl_down(pse, off);
      pde += __shfl_down(pde, off);
    }
    if (lane == 0) {
      es[((r0 + i) << 2) + h] = pse;
      ed[((r0 + i) << 2) + h] = pde;
    }
  }
}

__global__ void __launch_bounds__(256)
gat_out(const float* __restrict__ hfeat, const float* __restrict__ es, const float* __restrict__ ed,
        const float* __restrict__ gb, float* __restrict__ yout)
{
  __shared__ float exs[32][4];
  __shared__ float invden[4];
  const int tid = threadIdx.x;
  const int rbase = blockIdx.x << 5;
  if (tid < 128) {
    const int u = tid >> 2, h = tid & 3;
    float l = es[((rbase + u) << 2) + h] + ed[(rbase << 2) + h];
    exs[u][h] = (l < 0.0f) ? 0.2f * l : l;
  }
  __syncthreads();
  if (tid < 4) {
    const int h = tid;
    float m = -1e30f;
    for (int u = 0; u < 32; ++u) m = fmaxf(m, exs[u][h]);
    float s = 0.0f;
    for (int u = 0; u < 32; ++u) { float e = expf(exs[u][h] - m); exs[u][h] = e; s += e; }
    s += exs[0][h];                        // duplicate 0->0 edge
    invden[h] = 1.0f / (s + 1e-9f);
  }
  __syncthreads();
  const int h = tid >> 6;
  const float h0 = hfeat[(rbase << 8) + tid];
  float s = exs[0][h] * h0;
  for (int u = 0; u < 32; ++u)
    s += exs[u][h] * hfeat[((rbase + u) << 8) + tid];
  const float bias = gb[tid];
  const float inv1 = 1.0f / (1.0f + 1e-9f);
  yout[(rbase << 8) + tid] = gelu_t(s * invden[h] + bias);
  const float gv = gelu_t(h0 * inv1 + bias);
  for (int v = 1; v < 32; ++v)
    yout[((rbase + v) << 8) + tid] = gv;
}

// ---- launch ---------------------------------------------------------------
extern "C" void kernel_launch(void* const* d_in, const int* in_sizes, int n_in,
                              void* d_out, int out_size, void* d_ws, size_t ws_size,
                              hipStream_t stream) {
  (void)in_sizes; (void)n_in; (void)out_size; (void)ws_size;
  const float* states = (const float*)d_in[0];
  const float* Wx1 = (const float*)d_in[1];
  const float* Wh1 = (const float*)d_in[2];
  const float* b1  = (const float*)d_in[3];
  const float* Wx2 = (const float*)d_in[4];
  const float* Wh2 = (const float*)d_in[5];
  const float* b2  = (const float*)d_in[6];
  const float* gW1 = (const float*)d_in[7];
  const float* gas1 = (const float*)d_in[8];
  const float* gad1 = (const float*)d_in[9];
  const float* gb1 = (const float*)d_in[10];
  const float* gW2 = (const float*)d_in[11];
  const float* gas2 = (const float*)d_in[12];
  const float* gad2 = (const float*)d_in[13];
  const float* gb2 = (const float*)d_in[14];

  float* ws = (float*)d_ws;
  float* pair0 = ws;                       // 2*NB
  float* pair1 = ws + 2 * (size_t)NB;      // 2*NB
  float* xg    = ws + 4 * (size_t)NB;      // NB
  float* xT    = ws + 5 * (size_t)NB;      // 800*2048
  float* Wp1   = xT + 800 * 2048;          // 256*272*4 = 278528
  float* Wp2   = Wp1 + 278528;             // 256*512*4 = 524288
  unsigned* bar = (unsigned*)(Wp2 + 524288);
  // GAT aliases (pairs dead after lstm)
  float* y1    = pair0;
  float* hfeat = pair0 + NB;
  float* es    = pair1;
  float* ed    = pair1 + 2048 * 4;
  float* dout  = (float*)d_out;

  pack_w<<<dim3(2048), dim3(256), 0, stream>>>(Wx1, Wh1, Wx2, Wh2, Wp1, Wp2, bar);
  transpose_x<<<dim3(32 * 13), dim3(256), 0, stream>>>(states, xT);

  void* args[] = { (void*)&xT, (void*)&Wp1, (void*)&Wp2, (void*)&b1, (void*)&b2,
                   (void*)&pair0, (void*)&pair1, (void*)&xg, (void*)&bar };
  hipError_t err = hipLaunchCooperativeKernel((void*)lstm_fused, dim3(256), dim3(512),
                                              args, 0, stream);
  (void)err;

  gat_feat<<<dim3(256), dim3(256), 0, stream>>>(xg, gW1, gas1, gad1, hfeat, es, ed);
  gat_out<<<dim3(64), dim3(256), 0, stream>>>(hfeat, es, ed, gb1, y1);
  gat_feat<<<dim3(256), dim3(256), 0, stream>>>(y1, gW2, gas2, gad2, hfeat, es, ed);
  gat_out<<<dim3(64), dim3(256), 0, stream>>>(hfeat, es, ed, gb2, dout);
}